// Round 1
// 146.613 us; speedup vs baseline: 1.0255x; 1.0255x over previous
//
#include <hip/hip_runtime.h>

// Round 7: BI=8 x BJ=32 tile (same 256-thread / 4-wave block shape as the
// proven round-6 kernel) to halve the vertical halo over-read:
//   tp/rot tri2 + normals: (BI+1)/BI 1.25x -> 1.125x
//   verts:                 (BI+2)/BI 1.50x -> 1.25x
// Column halo doubles (9/288 vs 9/576 on faces) but is ~3%. Net -6% traffic.
// Staged per block (one barrier):
//   sT2/sR2: tri2 tp/rot rows i0-1..i0+7, cols j0..j0+31 as float4 chunks,
//            left-halo col (j0-1) as scalar dwords at float 288 of each row.
//   sV:      verts rows i0-1..i0+8, cols j0..j0+32 as float4 chunks,
//            left-halo col at float 100 of each row.
//   sN:      "vertex" normals rows i0..i0+8, cols j0..j0+32 (strided load9 +
//            per-item compute; reference indexes face normals by VERTEX id).
// t1/r1 are direct per-thread loads issued FIRST. All global loads issue
// before any LDS store so latency overlaps.
//
// Energy collapse (verified absmax==0 rounds 1-6):
//   sum_pq coeff[p][q](Dp.Dq) = 3(|u|^2+|w|^2+u.w) + (|a|^2+|b|^2+a.b),
//   a = n1.(R1-R2), b = n2.(R1-R2), H=1.
// Adjacency (verified): quad q=(i,j), f1=tri1=i*m+j, tri2=Q+i*m+j.
//   diag : f2=tri2(i,j):   u=t1r2-t2r2, w=t1r1-t2r0; n1=N[v01], n2=N[v10]
//   horiz: f2=tri2(i-1,j): u=t1r0-t2r0, w=t1r2-t2r1; n1=N[v00], n2=N[v01]
//   vert : f2=tri2(i,j-1): u=t1r0-t2r2, w=t1r1-t2r1; n1=N[v00], n2=N[v10]
// Clamp-garbage audit: halo/clamped slots only feed quads masked by
// (i<m && j<m), (i>0), (j>0).

#define BI 8
#define BJ 32
#define T2STRIDE 300   // floats: 288 main + 9 halo + 3 pad (1200B = 75*16)
#define VSTRIDE  104   // floats: 99 main(+1 pad hit by chunk 24) + 3 halo @100 + 1 pad (416B = 26*16)
#define NSTRIDE  99    // 33 normals * 3
#define T2_CH    648   // 9 rows * 72 chunks, per array
#define V_CH     250   // 10 rows * 25 chunks
#define MAIN_CH  (2 * T2_CH + V_CH)   // 1546
#define MAIN_ITERS 7                  // ceil(1546/256)
#define HALO_CNT 192                  // 2*9*9 face-halo + 10*3 vert-halo dwords
#define NORM_CNT 297                  // 9*33

struct __attribute__((aligned(4))) F4s { float a, b, c, d; };
struct F3 { float x, y, z; };
struct R9 { float v[9]; };

__device__ __forceinline__ R9 load9(const float* __restrict__ p) {
    R9 r;
    F4s u0 = *(const F4s*)p;
    F4s u1 = *(const F4s*)(p + 4);
    r.v[0] = u0.a; r.v[1] = u0.b; r.v[2] = u0.c; r.v[3] = u0.d;
    r.v[4] = u1.a; r.v[5] = u1.b; r.v[6] = u1.c; r.v[7] = u1.d;
    r.v[8] = p[8];
    return r;
}

__device__ __forceinline__ int imin(int a, int b) { return a < b ? a : b; }
__device__ __forceinline__ int imax(int a, int b) { return a > b ? a : b; }

__device__ __forceinline__ F3 normal_of(const R9& r) {
    float e1x = r.v[0] - r.v[3], e1y = r.v[1] - r.v[4], e1z = r.v[2] - r.v[5];
    float e2x = r.v[0] - r.v[6], e2y = r.v[1] - r.v[7], e2z = r.v[2] - r.v[8];
    float nx = e1y * e2z - e1z * e2y;
    float ny = e1z * e2x - e1x * e2z;
    float nz = e1x * e2y - e1y * e2x;
    float inv = 1.0f / sqrtf(nx * nx + ny * ny + nz * nz);
    F3 o; o.x = nx * inv; o.y = ny * inv; o.z = nz * inv; return o;
}

__device__ __forceinline__ float tri_area_p(const float* p, const float* q,
                                            const float* r) {
    float ax = q[0] - p[0], ay = q[1] - p[1], az = q[2] - p[2];
    float bx = r[0] - p[0], by = r[1] - p[1], bz = r[2] - p[2];
    float cx = ay * bz - az * by, cy = az * bx - ax * bz, cz = ax * by - ay * bx;
    return 0.5f * sqrtf(cx * cx + cy * cy + cz * cz);
}

__device__ __forceinline__ float edge_ew(const float* u1, const float* u2,
                                         const float* w1, const float* w2,
                                         const float* rA, const float* rB,
                                         const F3& n1, const F3& n2,
                                         const float* pa, const float* pb,
                                         float asum) {
    float ux = u1[0] - u2[0], uy = u1[1] - u2[1], uz = u1[2] - u2[2];
    float wx = w1[0] - w2[0], wy = w1[1] - w2[1], wz = w1[2] - w2[2];

    float d0 = rA[0] - rB[0], d1 = rA[1] - rB[1], d2 = rA[2] - rB[2];
    float d3 = rA[3] - rB[3], d4 = rA[4] - rB[4], d5 = rA[5] - rB[5];
    float d6 = rA[6] - rB[6], d7 = rA[7] - rB[7], d8 = rA[8] - rB[8];

    float ax = n1.x * d0 + n1.y * d3 + n1.z * d6;
    float ay = n1.x * d1 + n1.y * d4 + n1.z * d7;
    float az = n1.x * d2 + n1.y * d5 + n1.z * d8;
    float bx = n2.x * d0 + n2.y * d3 + n2.z * d6;
    float by = n2.x * d1 + n2.y * d4 + n2.z * d7;
    float bz = n2.x * d2 + n2.y * d5 + n2.z * d8;

    float uu = ux * ux + uy * uy + uz * uz;
    float ww = wx * wx + wy * wy + wz * wz;
    float uw = ux * wx + uy * wy + uz * wz;
    float aa = ax * ax + ay * ay + az * az;
    float bb = bx * bx + by * by + bz * bz;
    float ab = ax * bx + ay * by + az * bz;
    float energy = (3.0f * (uu + ww + uw) + (aa + bb + ab)) * (1.0f / 9.0f);

    float dx = pa[0] - pb[0], dy = pa[1] - pb[1], dz = pa[2] - pb[2];
    return energy * (dx * dx + dy * dy + dz * dz) / asum;
}

__global__ __launch_bounds__(256) void fused_kernel(
        const float* __restrict__ tp,    // (2Q,3,3)
        const float* __restrict__ rot,   // (2Q,3,3)
        const float* __restrict__ verts, // (n*n,3)
        double* __restrict__ partials,
        int n) {
    const int m = n - 1;
    const int Q = m * m;
    const int F = 2 * Q;
    const int V = n * n;
    const int tid = threadIdx.x;
    const int i0 = blockIdx.y * BI;
    const int j0 = blockIdx.x * BJ;
    const int w = tid >> 5;          // row within tile, 0..7
    const int l = tid & 31;          // col within tile, 0..31
    const int i = i0 + w;
    const int j = j0 + l;

    __shared__ __attribute__((aligned(16))) float sT2[9 * T2STRIDE];
    __shared__ __attribute__((aligned(16))) float sR2[9 * T2STRIDE];
    __shared__ __attribute__((aligned(16))) float sV[10 * VSTRIDE];
    __shared__ float sN[9 * NSTRIDE];
    __shared__ double sred[4];

    // ---- (1) t1/r1 direct loads, issued first ----
    int f1 = imin(i, m - 1) * m + imin(j, m - 1);
    R9 t1 = load9(tp  + (size_t)9 * f1);
    R9 r1 = load9(rot + (size_t)9 * f1);

    // ---- (2) main staged chunk loads (float4, lane-contiguous) ----
    float4 mval[MAIN_ITERS];
    float* mdst[MAIN_ITERS];
#pragma unroll
    for (int it = 0; it < MAIN_ITERS; ++it) {
        int s = tid + 256 * it;
        bool act = s < MAIN_CH;
        int sc = act ? s : 0;
        const float* gp;
        float* lp;
        if (sc < 2 * T2_CH) {
            int a = sc >= T2_CH;
            int t = a ? sc - T2_CH : sc;
            int r = t / 72, c = t - r * 72;
            int gi = imin(i0 - 1 + r, m - 1);           // can be -1: still >=0 index below
            int g = 9 * (Q + gi * m + j0) + 4 * c;
            g = imin(g, 9 * F - 4);
            gp = (a ? rot : tp) + g;
            lp = (a ? sR2 : sT2) + r * T2STRIDE + 4 * c;
        } else {
            int t = sc - 2 * T2_CH;
            int r = t / 25, c = t - r * 25;
            int vr = imax(imin(i0 - 1 + r, n - 1), 0);
            int g = 3 * (vr * n + j0) + 4 * c;
            g = imin(g, 3 * V - 4);
            gp = verts + g;
            lp = sV + r * VSTRIDE + 4 * c;
        }
        F4s u = *(const F4s*)gp;
        mval[it] = make_float4(u.a, u.b, u.c, u.d);
        mdst[it] = act ? lp : nullptr;
    }

    // ---- (3) halo scalar loads (left column j0-1) ----
    float hval = 0.0f;
    float* hdst = nullptr;
    if (tid < HALO_CNT) {
        if (tid < 162) {
            int a = tid >= 81;
            int t = a ? tid - 81 : tid;
            int r = t / 9, k = t - 9 * r;
            int gi = imin(i0 - 1 + r, m - 1);
            int face = Q + gi * m + (j0 - 1);           // >= Q-m-1 >= 0, < F
            hval = (a ? rot : tp)[9 * face + k];
            hdst = (a ? sR2 : sT2) + r * T2STRIDE + 288 + k;
        } else {
            int t = tid - 162;
            int r = t / 3, k = t - 3 * r;
            int vr = imax(imin(i0 - 1 + r, n - 1), 0);
            int g = imax(3 * (vr * n + (j0 - 1)) + k, 0);
            hval = verts[g];
            hdst = sV + r * VSTRIDE + 100 + k;
        }
    }

    // ---- (4) normal loads (strided load9) ----
    R9 nraw[2];
    int nofs[2];
#pragma unroll
    for (int it = 0; it < 2; ++it) {
        int s = tid + 256 * it;
        bool act = s < NORM_CNT;
        int sc = act ? s : 0;
        int r = sc / 33, c = sc - 33 * r;
        int gi = imin(i0 + r, n - 1);
        int gj = imin(j0 + c, n - 1);
        nraw[it] = load9(tp + (size_t)9 * (gi * n + gj));
        nofs[it] = act ? (r * NSTRIDE + 3 * c) : -1;
    }

    // ---- (5) LDS stores ----
#pragma unroll
    for (int it = 0; it < MAIN_ITERS; ++it)
        if (mdst[it]) *(float4*)mdst[it] = mval[it];
    if (hdst) *hdst = hval;
#pragma unroll
    for (int it = 0; it < 2; ++it) {
        if (nofs[it] >= 0) {
            F3 nm = normal_of(nraw[it]);
            sN[nofs[it]] = nm.x; sN[nofs[it] + 1] = nm.y; sN[nofs[it] + 2] = nm.z;
        }
    }

    __syncthreads();

    // ---- (6) compute ----
    double term = 0.0;
    if (i < m && j < m) {
        const float* t2c = sT2 + (w + 1) * T2STRIDE + 9 * l;
        const float* r2c = sR2 + (w + 1) * T2STRIDE + 9 * l;
        const float* th  = sT2 + w * T2STRIDE + 9 * l;
        const float* rh  = sR2 + w * T2STRIDE + 9 * l;
        int cm1 = l ? 9 * (l - 1) : 288;
        const float* tv  = sT2 + (w + 1) * T2STRIDE + cm1;
        const float* rv  = sR2 + (w + 1) * T2STRIDE + cm1;

        const float* p00 = sV + (w + 1) * VSTRIDE + 3 * l;
        const float* p01 = p00 + 3;
        const float* p10 = sV + (w + 2) * VSTRIDE + 3 * l;
        const float* p11 = p10 + 3;
        const float* pup = sV + w * VSTRIDE + 3 * (l + 1);
        int vm1 = l ? 3 * (l - 1) : 100;
        const float* plf = sV + (w + 2) * VSTRIDE + vm1;

        const float* na = sN + w * NSTRIDE + 3 * l;
        const float* nb = na + 3;
        const float* nc = sN + (w + 1) * NSTRIDE + 3 * l;
        F3 nA = { na[0], na[1], na[2] };
        F3 nB = { nb[0], nb[1], nb[2] };
        F3 nC = { nc[0], nc[1], nc[2] };

        float a1   = tri_area_p(p00, p10, p01);
        float a2c  = tri_area_p(p10, p11, p01);
        float a2up = tri_area_p(p00, p01, pup);
        float a2lf = tri_area_p(plf, p10, p00);

        float sum = edge_ew(t1.v + 6, t2c + 6, t1.v + 3, t2c + 0, r1.v, r2c,
                            nB, nC, p01, p10, a1 + a2c);
        float eh = edge_ew(t1.v + 0, th + 0, t1.v + 6, th + 3, r1.v, rh,
                           nA, nB, p00, p01, a1 + a2up);
        float ev = edge_ew(t1.v + 0, tv + 6, t1.v + 3, tv + 3, r1.v, rv,
                           nA, nC, p00, p10, a1 + a2lf);
        sum += (i > 0 ? eh : 0.0f);
        sum += (j > 0 ? ev : 0.0f);
        term = (double)sum;
    }

    // ---- (7) block reduction (full-wave64 shuffle; each wave64 spans 2 tile rows) ----
#pragma unroll
    for (int off = 32; off > 0; off >>= 1) term += __shfl_down(term, off, 64);
    {
        int lane64 = tid & 63, wv = tid >> 6;
        if (lane64 == 0) sred[wv] = term;
    }
    __syncthreads();
    if (tid == 0)
        partials[blockIdx.y * gridDim.x + blockIdx.x] =
            sred[0] + sred[1] + sred[2] + sred[3];
}

__global__ __launch_bounds__(256) void finalize_kernel(
        const double* __restrict__ partials, int P, float* __restrict__ out) {
    double s = 0.0;
    for (int i = threadIdx.x; i < P; i += 256) s += partials[i];
#pragma unroll
    for (int off = 32; off > 0; off >>= 1) s += __shfl_down(s, off, 64);
    __shared__ double sred[4];
    int lane = threadIdx.x & 63, wid = threadIdx.x >> 6;
    if (lane == 0) sred[wid] = s;
    __syncthreads();
    if (threadIdx.x == 0) out[0] = (float)(sred[0] + sred[1] + sred[2] + sred[3]);
}

extern "C" void kernel_launch(void* const* d_in, const int* in_sizes, int n_in,
                              void* d_out, int out_size, void* d_ws, size_t ws_size,
                              hipStream_t stream) {
    const float* tp    = (const float*)d_in[0];
    const float* rot   = (const float*)d_in[1];
    const float* verts = (const float*)d_in[2];

    int V = in_sizes[2] / 3;
    int n = (int)(sqrtf((float)V) + 0.5f);
    int m = n - 1;

    double* partials = (double*)d_ws;
    float*  out      = (float*)d_out;

    dim3 grid((m + BJ - 1) / BJ, (m + BI - 1) / BI);
    int P = grid.x * grid.y;
    fused_kernel<<<grid, 256, 0, stream>>>(tp, rot, verts, partials, n);
    finalize_kernel<<<1, 256, 0, stream>>>(partials, P, out);
}

// Round 2
// 145.538 us; speedup vs baseline: 1.0331x; 1.0074x over previous
//
#include <hip/hip_runtime.h>

// Round 8: global_load_lds staging (no VGPR round-trip) for the main tiles.
// BI=8 x BJ=32 tile, 256 threads / 4 wave64 per block (proven shape).
//
// Main LDS layouts are LINEAR so global_load_lds's wave-uniform-base +
// lane*16 destination rule holds:
//   sT2m/sR2m: 9 rows x 288 floats (72 chunks/row, no pad) = 648 chunks each.
//   sVm:       10 rows x 100 floats (25 chunks/row, 99 data + 1 pad) = 250 chunks.
// Wave-slot assignment (region id wave-uniform, chunk lane-linear):
//   ws 0..10  -> sT2m chunks ws*64+lane       (<648)
//   ws 11..21 -> sR2m chunks (ws-11)*64+lane  (<648)
//   ws 22..25 -> sVm  chunks (ws-22)*64+lane  (<250)
// Halos (left col j0-1) moved to separate small arrays sT2h/sR2h (stride 12)
// and sVh (stride 4), scalar-staged via registers as before.
// sN: "vertex" normals rows i0..i0+8, cols j0..j0+32 (strided load9 +
// per-item compute; reference indexes face normals by VERTEX id).
// t1/r1 direct per-thread register loads issued FIRST.
//
// Bank audit: sT2m stride 288 == 0 mod 32; compute reads at 9*l floats ->
// 9l mod 32 is a permutation (9 coprime 32); lanes l and l+32 alias 2-way
// (free per m136). sVm stride 100 == 4 mod 32, reads at 3*l -> permutation.
//
// Energy collapse (verified absmax==0 rounds 1-7):
//   sum_pq coeff[p][q](Dp.Dq) = 3(|u|^2+|w|^2+u.w) + (|a|^2+|b|^2+a.b),
//   a = n1.(R1-R2), b = n2.(R1-R2), H=1.
// Adjacency (verified): quad q=(i,j), f1=tri1=i*m+j, tri2=Q+i*m+j.
//   diag : f2=tri2(i,j):   u=t1r2-t2r2, w=t1r1-t2r0; n1=N[v01], n2=N[v10]
//   horiz: f2=tri2(i-1,j): u=t1r0-t2r0, w=t1r2-t2r1; n1=N[v00], n2=N[v01]
//   vert : f2=tri2(i,j-1): u=t1r0-t2r2, w=t1r1-t2r1; n1=N[v00], n2=N[v10]
// Clamp-garbage audit: halo/clamped slots only feed quads masked by
// (i<m && j<m), (i>0), (j>0). Same clamps as rounds 6-7.

#define BI 8
#define BJ 32
#define T2ROW 288     // floats per main row (72 chunks exactly)
#define VROW  100     // floats per main row (25 chunks; 99 data + 1 pad)
#define NSTRIDE 99    // 33 normals * 3
#define T2_CH 648     // 9 rows * 72 chunks, per array
#define V_CH  250     // 10 rows * 25 chunks
#define NORM_CNT 297  // 9*33
#define HALO_CNT 192  // 2*9*9 face-halo + 10*3 vert-halo dwords

struct __attribute__((aligned(4))) F4s { float a, b, c, d; };
struct F3 { float x, y, z; };
struct R9 { float v[9]; };

__device__ __forceinline__ R9 load9(const float* __restrict__ p) {
    R9 r;
    F4s u0 = *(const F4s*)p;
    F4s u1 = *(const F4s*)(p + 4);
    r.v[0] = u0.a; r.v[1] = u0.b; r.v[2] = u0.c; r.v[3] = u0.d;
    r.v[4] = u1.a; r.v[5] = u1.b; r.v[6] = u1.c; r.v[7] = u1.d;
    r.v[8] = p[8];
    return r;
}

__device__ __forceinline__ int imin(int a, int b) { return a < b ? a : b; }
__device__ __forceinline__ int imax(int a, int b) { return a > b ? a : b; }

__device__ __forceinline__ void gload_lds16(const float* gp, float* lp) {
    __builtin_amdgcn_global_load_lds(
        (const __attribute__((address_space(1))) void*)gp,
        (__attribute__((address_space(3))) void*)lp, 16, 0, 0);
}

__device__ __forceinline__ F3 normal_of(const R9& r) {
    float e1x = r.v[0] - r.v[3], e1y = r.v[1] - r.v[4], e1z = r.v[2] - r.v[5];
    float e2x = r.v[0] - r.v[6], e2y = r.v[1] - r.v[7], e2z = r.v[2] - r.v[8];
    float nx = e1y * e2z - e1z * e2y;
    float ny = e1z * e2x - e1x * e2z;
    float nz = e1x * e2y - e1y * e2x;
    float inv = 1.0f / sqrtf(nx * nx + ny * ny + nz * nz);
    F3 o; o.x = nx * inv; o.y = ny * inv; o.z = nz * inv; return o;
}

__device__ __forceinline__ float tri_area_p(const float* p, const float* q,
                                            const float* r) {
    float ax = q[0] - p[0], ay = q[1] - p[1], az = q[2] - p[2];
    float bx = r[0] - p[0], by = r[1] - p[1], bz = r[2] - p[2];
    float cx = ay * bz - az * by, cy = az * bx - ax * bz, cz = ax * by - ay * bx;
    return 0.5f * sqrtf(cx * cx + cy * cy + cz * cz);
}

__device__ __forceinline__ float edge_ew(const float* u1, const float* u2,
                                         const float* w1, const float* w2,
                                         const float* rA, const float* rB,
                                         const F3& n1, const F3& n2,
                                         const float* pa, const float* pb,
                                         float asum) {
    float ux = u1[0] - u2[0], uy = u1[1] - u2[1], uz = u1[2] - u2[2];
    float wx = w1[0] - w2[0], wy = w1[1] - w2[1], wz = w1[2] - w2[2];

    float d0 = rA[0] - rB[0], d1 = rA[1] - rB[1], d2 = rA[2] - rB[2];
    float d3 = rA[3] - rB[3], d4 = rA[4] - rB[4], d5 = rA[5] - rB[5];
    float d6 = rA[6] - rB[6], d7 = rA[7] - rB[7], d8 = rA[8] - rB[8];

    float ax = n1.x * d0 + n1.y * d3 + n1.z * d6;
    float ay = n1.x * d1 + n1.y * d4 + n1.z * d7;
    float az = n1.x * d2 + n1.y * d5 + n1.z * d8;
    float bx = n2.x * d0 + n2.y * d3 + n2.z * d6;
    float by = n2.x * d1 + n2.y * d4 + n2.z * d7;
    float bz = n2.x * d2 + n2.y * d5 + n2.z * d8;

    float uu = ux * ux + uy * uy + uz * uz;
    float ww = wx * wx + wy * wy + wz * wz;
    float uw = ux * wx + uy * wy + uz * wz;
    float aa = ax * ax + ay * ay + az * az;
    float bb = bx * bx + by * by + bz * bz;
    float ab = ax * bx + ay * by + az * bz;
    float energy = (3.0f * (uu + ww + uw) + (aa + bb + ab)) * (1.0f / 9.0f);

    float dx = pa[0] - pb[0], dy = pa[1] - pb[1], dz = pa[2] - pb[2];
    return energy * (dx * dx + dy * dy + dz * dz) / asum;
}

__global__ __launch_bounds__(256) void fused_kernel(
        const float* __restrict__ tp,    // (2Q,3,3)
        const float* __restrict__ rot,   // (2Q,3,3)
        const float* __restrict__ verts, // (n*n,3)
        double* __restrict__ partials,
        int n) {
    const int m = n - 1;
    const int Q = m * m;
    const int F = 2 * Q;
    const int V = n * n;
    const int tid = threadIdx.x;
    const int i0 = blockIdx.y * BI;
    const int j0 = blockIdx.x * BJ;
    const int w = tid >> 5;          // row within tile, 0..7
    const int l = tid & 31;          // col within tile, 0..31
    const int i = i0 + w;
    const int j = j0 + l;
    const int wv = tid >> 6;         // wave64 id, 0..3
    const int lane = tid & 63;

    __shared__ __attribute__((aligned(16))) float sT2m[9 * T2ROW];
    __shared__ __attribute__((aligned(16))) float sR2m[9 * T2ROW];
    __shared__ __attribute__((aligned(16))) float sVm[10 * VROW];
    __shared__ float sN[9 * NSTRIDE];
    __shared__ float sT2h[9 * 12];
    __shared__ float sR2h[9 * 12];
    __shared__ float sVh[10 * 4];
    __shared__ double sred[4];

    // ---- (1) t1/r1 direct register loads, issued first ----
    int f1 = imin(i, m - 1) * m + imin(j, m - 1);
    R9 t1 = load9(tp  + (size_t)9 * f1);
    R9 r1 = load9(rot + (size_t)9 * f1);

    // ---- (2) main staging: direct global->LDS, wave-slot per region ----
#pragma unroll
    for (int it = 0; it < 7; ++it) {
        int ws = it * 4 + wv;                 // wave-uniform slot id, 0..27
        if (ws < 22) {
            int a = ws >= 11;                 // wave-uniform
            int wl = a ? ws - 11 : ws;
            int chunk = wl * 64 + lane;       // lane-linear
            if (chunk < T2_CH) {
                int r = chunk / 72, c = chunk - r * 72;
                int gi = imin(i0 - 1 + r, m - 1);   // can be -1: face idx still >=0
                int g = 9 * (Q + gi * m + j0) + 4 * c;
                g = imin(g, 9 * F - 4);
                gload_lds16((a ? rot : tp) + g,
                            (a ? sR2m : sT2m) + chunk * 4);
            }
        } else if (ws < 26) {
            int chunk = (ws - 22) * 64 + lane;
            if (chunk < V_CH) {
                int r = chunk / 25, c = chunk - r * 25;
                int vr = imax(imin(i0 - 1 + r, n - 1), 0);
                int g = 3 * (vr * n + j0) + 4 * c;
                g = imin(g, 3 * V - 4);
                gload_lds16(verts + g, sVm + chunk * 4);
            }
        }
    }

    // ---- (3) halo scalar loads (left column j0-1) ----
    float hval = 0.0f;
    float* hdst = nullptr;
    if (tid < HALO_CNT) {
        if (tid < 162) {
            int a = tid >= 81;
            int t = a ? tid - 81 : tid;
            int r = t / 9, k = t - 9 * r;
            int gi = imin(i0 - 1 + r, m - 1);
            int face = Q + gi * m + (j0 - 1);       // >= Q-m-1 >= 0, < F
            hval = (a ? rot : tp)[9 * face + k];
            hdst = (a ? sR2h : sT2h) + r * 12 + k;
        } else {
            int t = tid - 162;
            int r = t / 3, k = t - 3 * r;
            int vr = imax(imin(i0 - 1 + r, n - 1), 0);
            int g = imax(3 * (vr * n + (j0 - 1)) + k, 0);
            hval = verts[g];
            hdst = sVh + r * 4 + k;
        }
    }

    // ---- (4) normal loads (strided load9) ----
    R9 nraw[2];
    int nofs[2];
#pragma unroll
    for (int it = 0; it < 2; ++it) {
        int s = tid + 256 * it;
        bool act = s < NORM_CNT;
        int sc = act ? s : 0;
        int r = sc / 33, c = sc - 33 * r;
        int gi = imin(i0 + r, n - 1);
        int gj = imin(j0 + c, n - 1);
        nraw[it] = load9(tp + (size_t)9 * (gi * n + gj));
        nofs[it] = act ? (r * NSTRIDE + 3 * c) : -1;
    }

    // ---- (5) LDS stores (halo + normals); main tiles land via DMA ----
    if (hdst) *hdst = hval;
#pragma unroll
    for (int it = 0; it < 2; ++it) {
        if (nofs[it] >= 0) {
            F3 nm = normal_of(nraw[it]);
            sN[nofs[it]] = nm.x; sN[nofs[it] + 1] = nm.y; sN[nofs[it] + 2] = nm.z;
        }
    }

    __syncthreads();   // drains vmcnt(0): global_load_lds complete here

    // ---- (6) compute ----
    double term = 0.0;
    if (i < m && j < m) {
        const float* t2c = sT2m + (w + 1) * T2ROW + 9 * l;
        const float* r2c = sR2m + (w + 1) * T2ROW + 9 * l;
        const float* th  = sT2m + w * T2ROW + 9 * l;
        const float* rh  = sR2m + w * T2ROW + 9 * l;
        const float* tv  = l ? sT2m + (w + 1) * T2ROW + 9 * (l - 1)
                             : sT2h + (w + 1) * 12;
        const float* rv  = l ? sR2m + (w + 1) * T2ROW + 9 * (l - 1)
                             : sR2h + (w + 1) * 12;

        const float* p00 = sVm + (w + 1) * VROW + 3 * l;
        const float* p01 = p00 + 3;
        const float* p10 = sVm + (w + 2) * VROW + 3 * l;
        const float* p11 = p10 + 3;
        const float* pup = sVm + w * VROW + 3 * (l + 1);
        const float* plf = l ? sVm + (w + 2) * VROW + 3 * (l - 1)
                             : sVh + (w + 2) * 4;

        const float* na = sN + w * NSTRIDE + 3 * l;
        const float* nb = na + 3;
        const float* nc = sN + (w + 1) * NSTRIDE + 3 * l;
        F3 nA = { na[0], na[1], na[2] };
        F3 nB = { nb[0], nb[1], nb[2] };
        F3 nC = { nc[0], nc[1], nc[2] };

        float a1   = tri_area_p(p00, p10, p01);
        float a2c  = tri_area_p(p10, p11, p01);
        float a2up = tri_area_p(p00, p01, pup);
        float a2lf = tri_area_p(plf, p10, p00);

        float sum = edge_ew(t1.v + 6, t2c + 6, t1.v + 3, t2c + 0, r1.v, r2c,
                            nB, nC, p01, p10, a1 + a2c);
        float eh = edge_ew(t1.v + 0, th + 0, t1.v + 6, th + 3, r1.v, rh,
                           nA, nB, p00, p01, a1 + a2up);
        float ev = edge_ew(t1.v + 0, tv + 6, t1.v + 3, tv + 3, r1.v, rv,
                           nA, nC, p00, p10, a1 + a2lf);
        sum += (i > 0 ? eh : 0.0f);
        sum += (j > 0 ? ev : 0.0f);
        term = (double)sum;
    }

    // ---- (7) block reduction (each wave64 spans 2 tile rows) ----
#pragma unroll
    for (int off = 32; off > 0; off >>= 1) term += __shfl_down(term, off, 64);
    if (lane == 0) sred[wv] = term;
    __syncthreads();
    if (tid == 0)
        partials[blockIdx.y * gridDim.x + blockIdx.x] =
            sred[0] + sred[1] + sred[2] + sred[3];
}

__global__ __launch_bounds__(256) void finalize_kernel(
        const double* __restrict__ partials, int P, float* __restrict__ out) {
    double s = 0.0;
    for (int i = threadIdx.x; i < P; i += 256) s += partials[i];
#pragma unroll
    for (int off = 32; off > 0; off >>= 1) s += __shfl_down(s, off, 64);
    __shared__ double sred[4];
    int lane = threadIdx.x & 63, wid = threadIdx.x >> 6;
    if (lane == 0) sred[wid] = s;
    __syncthreads();
    if (threadIdx.x == 0) out[0] = (float)(sred[0] + sred[1] + sred[2] + sred[3]);
}

extern "C" void kernel_launch(void* const* d_in, const int* in_sizes, int n_in,
                              void* d_out, int out_size, void* d_ws, size_t ws_size,
                              hipStream_t stream) {
    const float* tp    = (const float*)d_in[0];
    const float* rot   = (const float*)d_in[1];
    const float* verts = (const float*)d_in[2];

    int V = in_sizes[2] / 3;
    int n = (int)(sqrtf((float)V) + 0.5f);
    int m = n - 1;

    double* partials = (double*)d_ws;
    float*  out      = (float*)d_out;

    dim3 grid((m + BJ - 1) / BJ, (m + BI - 1) / BI);
    int P = grid.x * grid.y;
    fused_kernel<<<grid, 256, 0, stream>>>(tp, rot, verts, partials, n);
    finalize_kernel<<<1, 256, 0, stream>>>(partials, P, out);
}